// Round 5
// baseline (343.742 us; speedup 1.0000x reference)
//
#include <hip/hip_runtime.h>

#define D 128

typedef __attribute__((ext_vector_type(8))) short bf16x8;   // 8 bf16 = 4 VGPR
typedef __attribute__((ext_vector_type(4))) float f32x4;    // MFMA C/D

static __device__ __forceinline__ short f2bf(float f) {  // RNE bf16 bits
    union { float f; unsigned u; } v; v.f = f;
    const unsigned r = v.u + 0x7FFFu + ((v.u >> 16) & 1u);
    return (short)(r >> 16);
}
static __device__ __forceinline__ float bf2f(short s) {
    union { unsigned u; float f; } v;
    v.u = ((unsigned)(unsigned short)s) << 16;
    return v.f;
}

// ===== k_prep: nfeat->bf16 convert, W transpose->bf16, zero cnt/stats =====
__global__ __launch_bounds__(256) void k_prep(
    const float* __restrict__ nfeat, short* __restrict__ nfb,
    const float* __restrict__ W1, const float* __restrict__ W2,
    const float* __restrict__ We, short* __restrict__ Wt1,
    short* __restrict__ Wt2, short* __restrict__ Wte,
    int* __restrict__ cnt, float* __restrict__ stats,
    int N, int nbConv, int nbW)
{
    const int b = blockIdx.x, t = threadIdx.x;
    if (b < nbConv) {
        const int i = b * 256 + t;
        if (i < (N * D) / 4) {
            const float4 v = ((const float4*)nfeat)[i];
            short4 s;
            s.x = f2bf(v.x); s.y = f2bf(v.y); s.z = f2bf(v.z); s.w = f2bf(v.w);
            ((short4*)nfb)[i] = s;
        }
    } else if (b < nbConv + nbW) {
        const int i = (b - nbConv) * 256 + t;   // 0 .. 49151
        const int m = i >> 14;
        const int idx = i & 16383;
        const int k = idx >> 7, n = idx & 127;
        const float* W = (m == 0) ? W1 : (m == 1) ? W2 : We;
        short* Wt = (m == 0) ? Wt1 : (m == 1) ? Wt2 : Wte;
        Wt[n * 128 + k] = f2bf(W[k * 128 + n]);
    } else {
        const int i = (b - nbConv - nbW) * 256 + t;
        if (i * 4 < N) ((int4*)cnt)[i] = make_int4(0, 0, 0, 0);
        if (b == nbConv + nbW && t < 256) stats[t] = 0.f;
    }
}

// ================= CSR build =================
__global__ void k_hist(const int* __restrict__ dst, int* __restrict__ cnt, int E) {
    const int base = (blockIdx.x * 256 + threadIdx.x) * 4;
    if (base + 3 < E) {
        const int4 d4 = *(const int4*)(dst + base);
        atomicAdd(&cnt[d4.x], 1);
        atomicAdd(&cnt[d4.y], 1);
        atomicAdd(&cnt[d4.z], 1);
        atomicAdd(&cnt[d4.w], 1);
    } else {
        for (int e = base; e < E; ++e) atomicAdd(&cnt[dst[e]], 1);
    }
}

// ===== single-block multi-tile exclusive scan (replaces scan1/2/3) =====
__global__ __launch_bounds__(1024) void k_scan(
    const int* __restrict__ cnt, int* __restrict__ row_ptr,
    int* __restrict__ cursor, float* __restrict__ degf, int N)
{
    __shared__ int ws[17];
    const int t = threadIdx.x, lane = t & 63, wid = t >> 6;
    int carry = 0;
    const int ntiles = (N + 4095) / 4096;
    for (int tile = 0; tile < ntiles; ++tile) {
        const int base = tile * 4096 + t * 4;
        int4 v = make_int4(0, 0, 0, 0);
        if (base + 3 < N) v = *(const int4*)(cnt + base);
        else {
            if (base     < N) v.x = cnt[base];
            if (base + 1 < N) v.y = cnt[base + 1];
            if (base + 2 < N) v.z = cnt[base + 2];
            if (base + 3 < N) v.w = cnt[base + 3];
        }
        const int s = v.x + v.y + v.z + v.w;
        int incl = s;
        #pragma unroll
        for (int off = 1; off < 64; off <<= 1) {
            const int u = __shfl_up(incl, off);
            if (lane >= off) incl += u;
        }
        if (lane == 63) ws[wid] = incl;
        __syncthreads();
        if (t < 16) {
            const int wv = ws[t];
            int wincl = wv;
            #pragma unroll
            for (int off = 1; off < 16; off <<= 1) {
                const int u = __shfl_up(wincl, off);
                if (t >= off) wincl += u;
            }
            ws[t] = wincl - wv;
            if (t == 15) ws[16] = wincl;
        }
        __syncthreads();
        const int ex = carry + ws[wid] + (incl - s);
        if (base + 3 < N) {
            const int4 rp = make_int4(ex, ex + v.x, ex + v.x + v.y,
                                      ex + v.x + v.y + v.z);
            *(int4*)(row_ptr + base) = rp;
            *(int4*)(cursor + base)  = rp;
            *(float4*)(degf + base)  =
                make_float4((float)v.x, (float)v.y, (float)v.z, (float)v.w);
        } else {
            int run = ex;
            if (base < N)     { row_ptr[base]   = run; cursor[base]   = run; degf[base]   = (float)v.x; run += v.x; }
            if (base + 1 < N) { row_ptr[base+1] = run; cursor[base+1] = run; degf[base+1] = (float)v.y; run += v.y; }
            if (base + 2 < N) { row_ptr[base+2] = run; cursor[base+2] = run; degf[base+2] = (float)v.z; run += v.z; }
            if (base + 3 < N) { row_ptr[base+3] = run; cursor[base+3] = run; degf[base+3] = (float)v.w; }
        }
        carry += ws[16];
        __syncthreads();
    }
    if (t == 0) row_ptr[N] = carry;
}

__global__ void k_scatter(const int* __restrict__ src, const int* __restrict__ dst,
                          int* __restrict__ cursor,
                          int2* __restrict__ epair, int E) {
    const int base = (blockIdx.x * 256 + threadIdx.x) * 4;
    if (base + 3 < E) {
        const int4 d4 = *(const int4*)(dst + base);
        const int4 s4 = *(const int4*)(src + base);
        int p;
        p = atomicAdd(&cursor[d4.x], 1); epair[p] = make_int2(base + 0, s4.x);
        p = atomicAdd(&cursor[d4.y], 1); epair[p] = make_int2(base + 1, s4.y);
        p = atomicAdd(&cursor[d4.z], 1); epair[p] = make_int2(base + 2, s4.z);
        p = atomicAdd(&cursor[d4.w], 1); epair[p] = make_int2(base + 3, s4.w);
    } else {
        for (int e = base; e < E; ++e) {
            const int p = atomicAdd(&cursor[dst[e]], 1);
            epair[p] = make_int2(e, src[e]);
        }
    }
}

// ===== fused gather + h1: block = 64 nodes, 4 waves (16 nodes each) =====
// gather: x = nfeat[node] + sum nfb[src] -> LDS; agg_e = sum efeat -> global
// matmul: h1 = x @ W1 + b1 (bf16 MFMA from LDS), BN stats atomics
#define XS_STRIDE 136   // bf16 units; 272 B rows: conflict-free for b128 reads
__global__ __launch_bounds__(256) void k_gather_h1(
    const float* __restrict__ nfeat, const short* __restrict__ nfb,
    const float* __restrict__ efeat,
    const int* __restrict__ row_ptr, const int2* __restrict__ epair,
    const short* __restrict__ Wt1, const float* __restrict__ b1,
    short* __restrict__ agg_e, short* __restrict__ h1,
    float* __restrict__ stats, int N)
{
    __shared__ __attribute__((aligned(16))) short xs[64 * XS_STRIDE];
    const int t = threadIdx.x;
    const int lane = t & 63;
    const int w = t >> 6;
    const int h = lane >> 5;
    const int c = lane & 31;
    const int row0 = blockIdx.x * 64;

    // ---- gather phase ----
    for (int i = 0; i < 16; ++i) {
        const int nl = w * 16 + i;
        const int node = row0 + nl;
        if (node < N) {
            const int start = row_ptr[node];
            const int end   = row_ptr[node + 1];
            float4 an = make_float4(0.f, 0.f, 0.f, 0.f);
            float4 ae = make_float4(0.f, 0.f, 0.f, 0.f);
            for (int e = start + h; e < end; e += 2) {
                const int2 p = epair[e];
                const float4 ev = *(const float4*)(efeat + (size_t)p.x * D + c * 4);
                const short4 nv = *(const short4*)(nfb + (size_t)p.y * D + c * 4);
                ae.x += ev.x; ae.y += ev.y; ae.z += ev.z; ae.w += ev.w;
                an.x += bf2f(nv.x); an.y += bf2f(nv.y);
                an.z += bf2f(nv.z); an.w += bf2f(nv.w);
            }
            an.x += __shfl_xor(an.x, 32);
            an.y += __shfl_xor(an.y, 32);
            an.z += __shfl_xor(an.z, 32);
            an.w += __shfl_xor(an.w, 32);
            ae.x += __shfl_xor(ae.x, 32);
            ae.y += __shfl_xor(ae.y, 32);
            ae.z += __shfl_xor(ae.z, 32);
            ae.w += __shfl_xor(ae.w, 32);
            if (h == 0) {
                const float4 self = *(const float4*)(nfeat + (size_t)node * D + c * 4);
                short4 xv, ev2;
                xv.x = f2bf(self.x + an.x); xv.y = f2bf(self.y + an.y);
                xv.z = f2bf(self.z + an.z); xv.w = f2bf(self.w + an.w);
                ev2.x = f2bf(ae.x); ev2.y = f2bf(ae.y);
                ev2.z = f2bf(ae.z); ev2.w = f2bf(ae.w);
                *(short4*)(xs + nl * XS_STRIDE + c * 4) = xv;
                *(short4*)(agg_e + (size_t)node * D + c * 4) = ev2;
            }
        } else if (h == 0) {
            *(short4*)(xs + nl * XS_STRIDE + c * 4) = make_short4(0, 0, 0, 0);
        }
    }
    __syncthreads();

    // ---- matmul phase ----
    const int l15 = lane & 15;
    const int kg  = lane >> 4;

    bf16x8 bfr[4][2];
    #pragma unroll
    for (int kt = 0; kt < 4; ++kt)
        #pragma unroll
        for (int cf = 0; cf < 2; ++cf)
            bfr[kt][cf] = *(const bf16x8*)(Wt1 + (w * 32 + cf * 16 + l15) * D +
                                           kt * 32 + kg * 8);

    f32x4 acc[4][2];
    #pragma unroll
    for (int rt = 0; rt < 4; ++rt) { acc[rt][0] = (f32x4)0.f; acc[rt][1] = (f32x4)0.f; }

    #pragma unroll
    for (int rt = 0; rt < 4; ++rt) {
        #pragma unroll
        for (int kt = 0; kt < 4; ++kt) {
            const bf16x8 a = *(const bf16x8*)(xs + (rt * 16 + l15) * XS_STRIDE +
                                              kt * 32 + kg * 8);
            acc[rt][0] = __builtin_amdgcn_mfma_f32_16x16x32_bf16(a, bfr[kt][0], acc[rt][0], 0, 0, 0);
            acc[rt][1] = __builtin_amdgcn_mfma_f32_16x16x32_bf16(a, bfr[kt][1], acc[rt][1], 0, 0, 0);
        }
    }

    // ---- epilogue: bias, h1 write, BN stats ----
    const float bias0 = b1[w * 32 + l15];
    const float bias1 = b1[w * 32 + 16 + l15];
    float cs0 = 0.f, cq0 = 0.f, cs1 = 0.f, cq1 = 0.f;
    #pragma unroll
    for (int rt = 0; rt < 4; ++rt) {
        #pragma unroll
        for (int j = 0; j < 4; ++j) {
            const int row = row0 + rt * 16 + kg * 4 + j;
            if (row < N) {
                const float h0 = acc[rt][0][j] + bias0;
                const float hv = acc[rt][1][j] + bias1;
                h1[(size_t)row * D + w * 32 + l15]      = f2bf(h0);
                h1[(size_t)row * D + w * 32 + 16 + l15] = f2bf(hv);
                cs0 += h0; cq0 += h0 * h0;
                cs1 += hv; cq1 += hv * hv;
            }
        }
    }
    #pragma unroll
    for (int m = 16; m < 64; m <<= 1) {
        cs0 += __shfl_xor(cs0, m); cq0 += __shfl_xor(cq0, m);
        cs1 += __shfl_xor(cs1, m); cq1 += __shfl_xor(cq1, m);
    }
    if (lane < 16) {
        atomicAdd(stats + w * 32 + lane,            cs0);
        atomicAdd(stats + w * 32 + 16 + lane,       cs1);
        atomicAdd(stats + 128 + w * 32 + lane,      cq0);
        atomicAdd(stats + 128 + w * 32 + 16 + lane, cq1);
    }
}

// ==== k_out: out = relu(bn(h1))@W2 + agg_e@We + b2 + deg*be (bf16 MFMA) ====
__global__ __launch_bounds__(256) void k_out(const short* __restrict__ h1,
                                             const short* __restrict__ agg_e,
                                             const short* __restrict__ Wt2,
                                             const short* __restrict__ Wte,
                                             const float* __restrict__ stats,
                                             const float* __restrict__ gamma,
                                             const float* __restrict__ beta,
                                             const float* __restrict__ b2,
                                             const float* __restrict__ be,
                                             const float* __restrict__ degf,
                                             float* __restrict__ out, int N) {
    __shared__ float scs[128], shs[128];
    const int t = threadIdx.x;
    if (t < 128) {
        const float invN = 1.0f / (float)N;
        const float mu = stats[t] * invN;
        const float var = stats[128 + t] * invN - mu * mu;
        const float sc = gamma[t] * rsqrtf(var + 1e-5f);
        scs[t] = sc;
        shs[t] = beta[t] - mu * sc;
    }
    __syncthreads();

    const int lane = t & 63;
    const int w = t >> 6;
    const int l15 = lane & 15;
    const int kg = lane >> 4;
    const int row0 = blockIdx.x * 64;

    f32x4 acc[4][2];
    #pragma unroll
    for (int rt = 0; rt < 4; ++rt) { acc[rt][0] = (f32x4)0.f; acc[rt][1] = (f32x4)0.f; }

    bf16x8 bfr[4][2];

    // ---- phase A: relu(bn(h1)) @ W2 ----
    #pragma unroll
    for (int kt = 0; kt < 4; ++kt)
        #pragma unroll
        for (int cf = 0; cf < 2; ++cf)
            bfr[kt][cf] = *(const bf16x8*)(Wt2 + (w * 32 + cf * 16 + l15) * D +
                                           kt * 32 + kg * 8);

    #pragma unroll
    for (int rt = 0; rt < 4; ++rt) {
        const int row = row0 + rt * 16 + l15;
        #pragma unroll
        for (int kt = 0; kt < 4; ++kt) {
            bf16x8 raw = (bf16x8)(short)0;
            if (row < N)
                raw = *(const bf16x8*)(h1 + (size_t)row * D + kt * 32 + kg * 8);
            const int k0 = kt * 32 + kg * 8;
            const float4 sa = *(const float4*)(scs + k0);
            const float4 sb = *(const float4*)(scs + k0 + 4);
            const float4 ha = *(const float4*)(shs + k0);
            const float4 hb = *(const float4*)(shs + k0 + 4);
            bf16x8 afr;
            afr[0] = f2bf(fmaxf(bf2f(raw[0]) * sa.x + ha.x, 0.f));
            afr[1] = f2bf(fmaxf(bf2f(raw[1]) * sa.y + ha.y, 0.f));
            afr[2] = f2bf(fmaxf(bf2f(raw[2]) * sa.z + ha.z, 0.f));
            afr[3] = f2bf(fmaxf(bf2f(raw[3]) * sa.w + ha.w, 0.f));
            afr[4] = f2bf(fmaxf(bf2f(raw[4]) * sb.x + hb.x, 0.f));
            afr[5] = f2bf(fmaxf(bf2f(raw[5]) * sb.y + hb.y, 0.f));
            afr[6] = f2bf(fmaxf(bf2f(raw[6]) * sb.z + hb.z, 0.f));
            afr[7] = f2bf(fmaxf(bf2f(raw[7]) * sb.w + hb.w, 0.f));
            acc[rt][0] = __builtin_amdgcn_mfma_f32_16x16x32_bf16(afr, bfr[kt][0], acc[rt][0], 0, 0, 0);
            acc[rt][1] = __builtin_amdgcn_mfma_f32_16x16x32_bf16(afr, bfr[kt][1], acc[rt][1], 0, 0, 0);
        }
    }

    // ---- phase B: agg_e @ We ----
    #pragma unroll
    for (int kt = 0; kt < 4; ++kt)
        #pragma unroll
        for (int cf = 0; cf < 2; ++cf)
            bfr[kt][cf] = *(const bf16x8*)(Wte + (w * 32 + cf * 16 + l15) * D +
                                           kt * 32 + kg * 8);

    #pragma unroll
    for (int rt = 0; rt < 4; ++rt) {
        const int row = row0 + rt * 16 + l15;
        bf16x8 a0 = (bf16x8)(short)0, a1 = a0, a2 = a0, a3 = a0;
        if (row < N) {
            const short* ap = agg_e + (size_t)row * D + kg * 8;
            a0 = *(const bf16x8*)(ap);
            a1 = *(const bf16x8*)(ap + 32);
            a2 = *(const bf16x8*)(ap + 64);
            a3 = *(const bf16x8*)(ap + 96);
        }
        acc[rt][0] = __builtin_amdgcn_mfma_f32_16x16x32_bf16(a0, bfr[0][0], acc[rt][0], 0, 0, 0);
        acc[rt][1] = __builtin_amdgcn_mfma_f32_16x16x32_bf16(a0, bfr[0][1], acc[rt][1], 0, 0, 0);
        acc[rt][0] = __builtin_amdgcn_mfma_f32_16x16x32_bf16(a1, bfr[1][0], acc[rt][0], 0, 0, 0);
        acc[rt][1] = __builtin_amdgcn_mfma_f32_16x16x32_bf16(a1, bfr[1][1], acc[rt][1], 0, 0, 0);
        acc[rt][0] = __builtin_amdgcn_mfma_f32_16x16x32_bf16(a2, bfr[2][0], acc[rt][0], 0, 0, 0);
        acc[rt][1] = __builtin_amdgcn_mfma_f32_16x16x32_bf16(a2, bfr[2][1], acc[rt][1], 0, 0, 0);
        acc[rt][0] = __builtin_amdgcn_mfma_f32_16x16x32_bf16(a3, bfr[3][0], acc[rt][0], 0, 0, 0);
        acc[rt][1] = __builtin_amdgcn_mfma_f32_16x16x32_bf16(a3, bfr[3][1], acc[rt][1], 0, 0, 0);
    }

    // ---- epilogue ----
    const float b2_0 = b2[w * 32 + l15];
    const float b2_1 = b2[w * 32 + 16 + l15];
    const float be_0 = be[w * 32 + l15];
    const float be_1 = be[w * 32 + 16 + l15];
    #pragma unroll
    for (int rt = 0; rt < 4; ++rt) {
        const int rbase = row0 + rt * 16 + kg * 4;
        float dgv[4];
        if (rbase + 3 < N) {
            *(float4*)dgv = *(const float4*)(degf + rbase);
        } else {
            #pragma unroll
            for (int j = 0; j < 4; ++j)
                dgv[j] = (rbase + j < N) ? degf[rbase + j] : 0.f;
        }
        #pragma unroll
        for (int j = 0; j < 4; ++j) {
            const int row = rbase + j;
            if (row < N) {
                out[(size_t)row * D + w * 32 + l15] =
                    acc[rt][0][j] + b2_0 + dgv[j] * be_0;
                out[(size_t)row * D + w * 32 + 16 + l15] =
                    acc[rt][1][j] + b2_1 + dgv[j] * be_1;
            }
        }
    }
}

extern "C" void kernel_launch(void* const* d_in, const int* in_sizes, int n_in,
                              void* d_out, int out_size, void* d_ws, size_t ws_size,
                              hipStream_t stream) {
    const float* nfeat = (const float*)d_in[0];
    const float* efeat = (const float*)d_in[1];
    const int*   src   = (const int*)d_in[2];
    const int*   dst   = (const int*)d_in[3];
    const float* W1    = (const float*)d_in[4];
    const float* b1    = (const float*)d_in[5];
    const float* gamma = (const float*)d_in[6];
    const float* beta  = (const float*)d_in[7];
    const float* W2    = (const float*)d_in[8];
    const float* b2    = (const float*)d_in[9];
    const float* We    = (const float*)d_in[10];
    const float* be    = (const float*)d_in[11];
    float* out = (float*)d_out;

    const int N = in_sizes[0] / D;
    const int E = in_sizes[2];
    const size_t ND = (size_t)N * D;

    // workspace layout — every segment a multiple of 16 B, so all 16B-aligned
    short* nfb    = (short*)d_ws;                // N*D bf16
    short* agg_e  = nfb + ND;                    // N*D bf16
    short* h1     = agg_e + ND;                  // N*D bf16
    short* Wt1    = h1 + ND;                     // 16384
    short* Wt2    = Wt1 + 16384;
    short* Wte    = Wt2 + 16384;
    float* stats  = (float*)(Wte + 16384);       // 256
    float* degf   = stats + 256;                 // N
    int*   row_ptr= (int*)(degf + N);            // N+16
    int*   cursor = row_ptr + (N + 16);          // N+16
    int*   cnt    = cursor + (N + 16);           // N+16
    int2*  epair  = (int2*)(cnt + (N + 16));     // E

    const int nbConv = ((N * D) / 4 + 255) / 256;
    const int nbW    = 192;
    const int nbZ    = (N / 4 + 255) / 256;
    const int ebl4   = (E / 4 + 255) / 256;
    const int nb     = (N + 63) / 64;

    k_prep<<<nbConv + nbW + nbZ, 256, 0, stream>>>(nfeat, nfb, W1, W2, We,
                                                   Wt1, Wt2, Wte, cnt, stats,
                                                   N, nbConv, nbW);
    k_hist<<<ebl4, 256, 0, stream>>>(dst, cnt, E);
    k_scan<<<1, 1024, 0, stream>>>(cnt, row_ptr, cursor, degf, N);
    k_scatter<<<ebl4, 256, 0, stream>>>(src, dst, cursor, epair, E);
    k_gather_h1<<<nb, 256, 0, stream>>>(nfeat, nfb, efeat, row_ptr, epair,
                                        Wt1, b1, agg_e, h1, stats, N);
    k_out<<<nb, 256, 0, stream>>>(h1, agg_e, Wt2, Wte, stats, gamma, beta,
                                  b2, be, degf, out, N);
}

// Round 6
// 285.805 us; speedup vs baseline: 1.2027x; 1.2027x over previous
//
#include <hip/hip_runtime.h>

#define D 128

typedef __attribute__((ext_vector_type(8))) short bf16x8;   // 8 bf16 = 4 VGPR
typedef __attribute__((ext_vector_type(4))) float f32x4;    // MFMA C/D

static __device__ __forceinline__ short f2bf(float f) {  // RNE bf16 bits
    union { float f; unsigned u; } v; v.f = f;
    const unsigned r = v.u + 0x7FFFu + ((v.u >> 16) & 1u);
    return (short)(r >> 16);
}
static __device__ __forceinline__ float bf2f(short s) {
    union { unsigned u; float f; } v;
    v.u = ((unsigned)(unsigned short)s) << 16;
    return v.f;
}

// ===== k_prep: nfeat->bf16 convert, W transpose->bf16, zero cnt/stats =====
__global__ __launch_bounds__(256) void k_prep(
    const float* __restrict__ nfeat, short* __restrict__ nfb,
    const float* __restrict__ W1, const float* __restrict__ W2,
    const float* __restrict__ We, short* __restrict__ Wt1,
    short* __restrict__ Wt2, short* __restrict__ Wte,
    int* __restrict__ cnt, float* __restrict__ stats,
    int N, int nbConv, int nbW)
{
    const int b = blockIdx.x, t = threadIdx.x;
    if (b < nbConv) {
        const int i = b * 256 + t;
        if (i < (N * D) / 4) {
            const float4 v = ((const float4*)nfeat)[i];
            short4 s;
            s.x = f2bf(v.x); s.y = f2bf(v.y); s.z = f2bf(v.z); s.w = f2bf(v.w);
            ((short4*)nfb)[i] = s;
        }
    } else if (b < nbConv + nbW) {
        const int i = (b - nbConv) * 256 + t;   // 0 .. 49151
        const int m = i >> 14;
        const int idx = i & 16383;
        const int k = idx >> 7, n = idx & 127;
        const float* W = (m == 0) ? W1 : (m == 1) ? W2 : We;
        short* Wt = (m == 0) ? Wt1 : (m == 1) ? Wt2 : Wte;
        Wt[n * 128 + k] = f2bf(W[k * 128 + n]);
    } else {
        const int i = (b - nbConv - nbW) * 256 + t;
        if (i * 4 < N) ((int4*)cnt)[i] = make_int4(0, 0, 0, 0);
        if (b == nbConv + nbW && t < 256) stats[t] = 0.f;
    }
}

// ================= CSR build =================
__global__ void k_hist(const int* __restrict__ dst, int* __restrict__ cnt, int E) {
    const int base = (blockIdx.x * 256 + threadIdx.x) * 4;
    if (base + 3 < E) {
        const int4 d4 = *(const int4*)(dst + base);
        atomicAdd(&cnt[d4.x], 1);
        atomicAdd(&cnt[d4.y], 1);
        atomicAdd(&cnt[d4.z], 1);
        atomicAdd(&cnt[d4.w], 1);
    } else {
        for (int e = base; e < E; ++e) atomicAdd(&cnt[dst[e]], 1);
    }
}

// ===== single-block multi-tile exclusive scan =====
__global__ __launch_bounds__(1024) void k_scan(
    const int* __restrict__ cnt, int* __restrict__ row_ptr,
    int* __restrict__ cursor, float* __restrict__ degf, int N)
{
    __shared__ int ws[17];
    const int t = threadIdx.x, lane = t & 63, wid = t >> 6;
    int carry = 0;
    const int ntiles = (N + 4095) / 4096;
    for (int tile = 0; tile < ntiles; ++tile) {
        const int base = tile * 4096 + t * 4;
        int4 v = make_int4(0, 0, 0, 0);
        if (base + 3 < N) v = *(const int4*)(cnt + base);
        else {
            if (base     < N) v.x = cnt[base];
            if (base + 1 < N) v.y = cnt[base + 1];
            if (base + 2 < N) v.z = cnt[base + 2];
            if (base + 3 < N) v.w = cnt[base + 3];
        }
        const int s = v.x + v.y + v.z + v.w;
        int incl = s;
        #pragma unroll
        for (int off = 1; off < 64; off <<= 1) {
            const int u = __shfl_up(incl, off);
            if (lane >= off) incl += u;
        }
        if (lane == 63) ws[wid] = incl;
        __syncthreads();
        if (t < 16) {
            const int wv = ws[t];
            int wincl = wv;
            #pragma unroll
            for (int off = 1; off < 16; off <<= 1) {
                const int u = __shfl_up(wincl, off);
                if (t >= off) wincl += u;
            }
            ws[t] = wincl - wv;
            if (t == 15) ws[16] = wincl;
        }
        __syncthreads();
        const int ex = carry + ws[wid] + (incl - s);
        if (base + 3 < N) {
            const int4 rp = make_int4(ex, ex + v.x, ex + v.x + v.y,
                                      ex + v.x + v.y + v.z);
            *(int4*)(row_ptr + base) = rp;
            *(int4*)(cursor + base)  = rp;
            *(float4*)(degf + base)  =
                make_float4((float)v.x, (float)v.y, (float)v.z, (float)v.w);
        } else {
            int run = ex;
            if (base < N)     { row_ptr[base]   = run; cursor[base]   = run; degf[base]   = (float)v.x; run += v.x; }
            if (base + 1 < N) { row_ptr[base+1] = run; cursor[base+1] = run; degf[base+1] = (float)v.y; run += v.y; }
            if (base + 2 < N) { row_ptr[base+2] = run; cursor[base+2] = run; degf[base+2] = (float)v.z; run += v.z; }
            if (base + 3 < N) { row_ptr[base+3] = run; cursor[base+3] = run; degf[base+3] = (float)v.w; }
        }
        carry += ws[16];
        __syncthreads();
    }
    if (t == 0) row_ptr[N] = carry;
}

__global__ void k_scatter(const int* __restrict__ src, const int* __restrict__ dst,
                          int* __restrict__ cursor,
                          int2* __restrict__ epair, int E) {
    const int base = (blockIdx.x * 256 + threadIdx.x) * 4;
    if (base + 3 < E) {
        const int4 d4 = *(const int4*)(dst + base);
        const int4 s4 = *(const int4*)(src + base);
        int p;
        p = atomicAdd(&cursor[d4.x], 1); epair[p] = make_int2(base + 0, s4.x);
        p = atomicAdd(&cursor[d4.y], 1); epair[p] = make_int2(base + 1, s4.y);
        p = atomicAdd(&cursor[d4.z], 1); epair[p] = make_int2(base + 2, s4.z);
        p = atomicAdd(&cursor[d4.w], 1); epair[p] = make_int2(base + 3, s4.w);
    } else {
        for (int e = base; e < E; ++e) {
            const int p = atomicAdd(&cursor[dst[e]], 1);
            epair[p] = make_int2(e, src[e]);
        }
    }
}

// ===== gather: 1 wave/node, 2 half-waves x 2-deep pipeline (4 edges in flight)
// writes xbuf = bf16(nfeat[node] + sum nfb[src]), agg_e = bf16(sum efeat[e])
__global__ __launch_bounds__(256) void k_gather(
    const float* __restrict__ nfeat, const short* __restrict__ nfb,
    const float* __restrict__ efeat,
    const int* __restrict__ row_ptr, const int2* __restrict__ epair,
    short* __restrict__ xbuf, short* __restrict__ agg_e, int N)
{
    const int t = threadIdx.x;
    const int lane = t & 63;
    const int h = lane >> 5;      // half-wave: edges start+h, +2, ...
    const int c = lane & 31;      // float4 chunk of the 128-dim row
    const int node = blockIdx.x * 4 + (t >> 6);
    if (node >= N) return;

    const int start = row_ptr[node];
    const int end   = row_ptr[node + 1];

    float4 an = make_float4(0.f, 0.f, 0.f, 0.f);
    float4 ae = make_float4(0.f, 0.f, 0.f, 0.f);
    int e = start + h;
    for (; e + 2 < end; e += 4) {   // 2 edges per half-wave in flight
        const int2 p0 = epair[e];
        const int2 p1 = epair[e + 2];
        const float4 ev0 = *(const float4*)(efeat + (size_t)p0.x * D + c * 4);
        const short4 nv0 = *(const short4*)(nfb + (size_t)p0.y * D + c * 4);
        const float4 ev1 = *(const float4*)(efeat + (size_t)p1.x * D + c * 4);
        const short4 nv1 = *(const short4*)(nfb + (size_t)p1.y * D + c * 4);
        ae.x += ev0.x + ev1.x; ae.y += ev0.y + ev1.y;
        ae.z += ev0.z + ev1.z; ae.w += ev0.w + ev1.w;
        an.x += bf2f(nv0.x) + bf2f(nv1.x);
        an.y += bf2f(nv0.y) + bf2f(nv1.y);
        an.z += bf2f(nv0.z) + bf2f(nv1.z);
        an.w += bf2f(nv0.w) + bf2f(nv1.w);
    }
    if (e < end) {
        const int2 p0 = epair[e];
        const float4 ev0 = *(const float4*)(efeat + (size_t)p0.x * D + c * 4);
        const short4 nv0 = *(const short4*)(nfb + (size_t)p0.y * D + c * 4);
        ae.x += ev0.x; ae.y += ev0.y; ae.z += ev0.z; ae.w += ev0.w;
        an.x += bf2f(nv0.x); an.y += bf2f(nv0.y);
        an.z += bf2f(nv0.z); an.w += bf2f(nv0.w);
    }
    an.x += __shfl_xor(an.x, 32);
    an.y += __shfl_xor(an.y, 32);
    an.z += __shfl_xor(an.z, 32);
    an.w += __shfl_xor(an.w, 32);
    ae.x += __shfl_xor(ae.x, 32);
    ae.y += __shfl_xor(ae.y, 32);
    ae.z += __shfl_xor(ae.z, 32);
    ae.w += __shfl_xor(ae.w, 32);

    if (h == 0) {
        const float4 self = *(const float4*)(nfeat + (size_t)node * D + c * 4);
        short4 xv, ev2;
        xv.x = f2bf(self.x + an.x); xv.y = f2bf(self.y + an.y);
        xv.z = f2bf(self.z + an.z); xv.w = f2bf(self.w + an.w);
        ev2.x = f2bf(ae.x); ev2.y = f2bf(ae.y);
        ev2.z = f2bf(ae.z); ev2.w = f2bf(ae.w);
        *(short4*)(xbuf  + (size_t)node * D + c * 4) = xv;
        *(short4*)(agg_e + (size_t)node * D + c * 4) = ev2;
    }
}

// ======= k_h1: h1 = xbuf @ W1 + b1 (bf16 MFMA), + BN stats atomics =======
// 64 rows/block, 4 waves; wave w owns cols [w*32, w*32+32)
// NOTE: xbuf and h1 alias (reads complete before epilogue writes) — no restrict
__global__ __launch_bounds__(256) void k_h1(const short* xbuf,
                                            const short* __restrict__ Wt1,
                                            const float* __restrict__ b1,
                                            short* h1,
                                            float* __restrict__ stats, int N) {
    const int t = threadIdx.x;
    const int lane = t & 63;
    const int w = t >> 6;
    const int l15 = lane & 15;
    const int kg = lane >> 4;
    const int row0 = blockIdx.x * 64;

    bf16x8 bfr[4][2];
    #pragma unroll
    for (int kt = 0; kt < 4; ++kt)
        #pragma unroll
        for (int cf = 0; cf < 2; ++cf)
            bfr[kt][cf] = *(const bf16x8*)(Wt1 + (w * 32 + cf * 16 + l15) * D +
                                           kt * 32 + kg * 8);

    f32x4 acc[4][2];
    #pragma unroll
    for (int rt = 0; rt < 4; ++rt) { acc[rt][0] = (f32x4)0.f; acc[rt][1] = (f32x4)0.f; }

    #pragma unroll
    for (int rt = 0; rt < 4; ++rt) {
        const int row = row0 + rt * 16 + l15;
        bf16x8 a0 = (bf16x8)(short)0, a1 = a0, a2 = a0, a3 = a0;
        if (row < N) {
            const short* xp = xbuf + (size_t)row * D + kg * 8;
            a0 = *(const bf16x8*)(xp);
            a1 = *(const bf16x8*)(xp + 32);
            a2 = *(const bf16x8*)(xp + 64);
            a3 = *(const bf16x8*)(xp + 96);
        }
        acc[rt][0] = __builtin_amdgcn_mfma_f32_16x16x32_bf16(a0, bfr[0][0], acc[rt][0], 0, 0, 0);
        acc[rt][1] = __builtin_amdgcn_mfma_f32_16x16x32_bf16(a0, bfr[0][1], acc[rt][1], 0, 0, 0);
        acc[rt][0] = __builtin_amdgcn_mfma_f32_16x16x32_bf16(a1, bfr[1][0], acc[rt][0], 0, 0, 0);
        acc[rt][1] = __builtin_amdgcn_mfma_f32_16x16x32_bf16(a1, bfr[1][1], acc[rt][1], 0, 0, 0);
        acc[rt][0] = __builtin_amdgcn_mfma_f32_16x16x32_bf16(a2, bfr[2][0], acc[rt][0], 0, 0, 0);
        acc[rt][1] = __builtin_amdgcn_mfma_f32_16x16x32_bf16(a2, bfr[2][1], acc[rt][1], 0, 0, 0);
        acc[rt][0] = __builtin_amdgcn_mfma_f32_16x16x32_bf16(a3, bfr[3][0], acc[rt][0], 0, 0, 0);
        acc[rt][1] = __builtin_amdgcn_mfma_f32_16x16x32_bf16(a3, bfr[3][1], acc[rt][1], 0, 0, 0);
    }

    const float bias0 = b1[w * 32 + l15];
    const float bias1 = b1[w * 32 + 16 + l15];
    float cs0 = 0.f, cq0 = 0.f, cs1 = 0.f, cq1 = 0.f;
    #pragma unroll
    for (int rt = 0; rt < 4; ++rt) {
        #pragma unroll
        for (int j = 0; j < 4; ++j) {
            const int row = row0 + rt * 16 + kg * 4 + j;
            if (row < N) {
                const float h0 = acc[rt][0][j] + bias0;
                const float hv = acc[rt][1][j] + bias1;
                h1[(size_t)row * D + w * 32 + l15]      = f2bf(h0);
                h1[(size_t)row * D + w * 32 + 16 + l15] = f2bf(hv);
                cs0 += h0; cq0 += h0 * h0;
                cs1 += hv; cq1 += hv * hv;
            }
        }
    }
    #pragma unroll
    for (int m = 16; m < 64; m <<= 1) {
        cs0 += __shfl_xor(cs0, m); cq0 += __shfl_xor(cq0, m);
        cs1 += __shfl_xor(cs1, m); cq1 += __shfl_xor(cq1, m);
    }
    if (lane < 16) {
        atomicAdd(stats + w * 32 + lane,            cs0);
        atomicAdd(stats + w * 32 + 16 + lane,       cs1);
        atomicAdd(stats + 128 + w * 32 + lane,      cq0);
        atomicAdd(stats + 128 + w * 32 + 16 + lane, cq1);
    }
}

// ==== k_out: out = relu(bn(h1))@W2 + agg_e@We + b2 + deg*be (bf16 MFMA) ====
__global__ __launch_bounds__(256) void k_out(const short* __restrict__ h1,
                                             const short* __restrict__ agg_e,
                                             const short* __restrict__ Wt2,
                                             const short* __restrict__ Wte,
                                             const float* __restrict__ stats,
                                             const float* __restrict__ gamma,
                                             const float* __restrict__ beta,
                                             const float* __restrict__ b2,
                                             const float* __restrict__ be,
                                             const float* __restrict__ degf,
                                             float* __restrict__ out, int N) {
    __shared__ float scs[128], shs[128];
    const int t = threadIdx.x;
    if (t < 128) {
        const float invN = 1.0f / (float)N;
        const float mu = stats[t] * invN;
        const float var = stats[128 + t] * invN - mu * mu;
        const float sc = gamma[t] * rsqrtf(var + 1e-5f);
        scs[t] = sc;
        shs[t] = beta[t] - mu * sc;
    }
    __syncthreads();

    const int lane = t & 63;
    const int w = t >> 6;
    const int l15 = lane & 15;
    const int kg = lane >> 4;
    const int row0 = blockIdx.x * 64;

    f32x4 acc[4][2];
    #pragma unroll
    for (int rt = 0; rt < 4; ++rt) { acc[rt][0] = (f32x4)0.f; acc[rt][1] = (f32x4)0.f; }

    bf16x8 bfr[4][2];

    // ---- phase A: relu(bn(h1)) @ W2 ----
    #pragma unroll
    for (int kt = 0; kt < 4; ++kt)
        #pragma unroll
        for (int cf = 0; cf < 2; ++cf)
            bfr[kt][cf] = *(const bf16x8*)(Wt2 + (w * 32 + cf * 16 + l15) * D +
                                           kt * 32 + kg * 8);

    #pragma unroll
    for (int rt = 0; rt < 4; ++rt) {
        const int row = row0 + rt * 16 + l15;
        #pragma unroll
        for (int kt = 0; kt < 4; ++kt) {
            bf16x8 raw = (bf16x8)(short)0;
            if (row < N)
                raw = *(const bf16x8*)(h1 + (size_t)row * D + kt * 32 + kg * 8);
            const int k0 = kt * 32 + kg * 8;
            const float4 sa = *(const float4*)(scs + k0);
            const float4 sb = *(const float4*)(scs + k0 + 4);
            const float4 ha = *(const float4*)(shs + k0);
            const float4 hb = *(const float4*)(shs + k0 + 4);
            bf16x8 afr;
            afr[0] = f2bf(fmaxf(bf2f(raw[0]) * sa.x + ha.x, 0.f));
            afr[1] = f2bf(fmaxf(bf2f(raw[1]) * sa.y + ha.y, 0.f));
            afr[2] = f2bf(fmaxf(bf2f(raw[2]) * sa.z + ha.z, 0.f));
            afr[3] = f2bf(fmaxf(bf2f(raw[3]) * sa.w + ha.w, 0.f));
            afr[4] = f2bf(fmaxf(bf2f(raw[4]) * sb.x + hb.x, 0.f));
            afr[5] = f2bf(fmaxf(bf2f(raw[5]) * sb.y + hb.y, 0.f));
            afr[6] = f2bf(fmaxf(bf2f(raw[6]) * sb.z + hb.z, 0.f));
            afr[7] = f2bf(fmaxf(bf2f(raw[7]) * sb.w + hb.w, 0.f));
            acc[rt][0] = __builtin_amdgcn_mfma_f32_16x16x32_bf16(afr, bfr[kt][0], acc[rt][0], 0, 0, 0);
            acc[rt][1] = __builtin_amdgcn_mfma_f32_16x16x32_bf16(afr, bfr[kt][1], acc[rt][1], 0, 0, 0);
        }
    }

    // ---- phase B: agg_e @ We ----
    #pragma unroll
    for (int kt = 0; kt < 4; ++kt)
        #pragma unroll
        for (int cf = 0; cf < 2; ++cf)
            bfr[kt][cf] = *(const bf16x8*)(Wte + (w * 32 + cf * 16 + l15) * D +
                                           kt * 32 + kg * 8);

    #pragma unroll
    for (int rt = 0; rt < 4; ++rt) {
        const int row = row0 + rt * 16 + l15;
        bf16x8 a0 = (bf16x8)(short)0, a1 = a0, a2 = a0, a3 = a0;
        if (row < N) {
            const short* ap = agg_e + (size_t)row * D + kg * 8;
            a0 = *(const bf16x8*)(ap);
            a1 = *(const bf16x8*)(ap + 32);
            a2 = *(const bf16x8*)(ap + 64);
            a3 = *(const bf16x8*)(ap + 96);
        }
        acc[rt][0] = __builtin_amdgcn_mfma_f32_16x16x32_bf16(a0, bfr[0][0], acc[rt][0], 0, 0, 0);
        acc[rt][1] = __builtin_amdgcn_mfma_f32_16x16x32_bf16(a0, bfr[0][1], acc[rt][1], 0, 0, 0);
        acc[rt][0] = __builtin_amdgcn_mfma_f32_16x16x32_bf16(a1, bfr[1][0], acc[rt][0], 0, 0, 0);
        acc[rt][1] = __builtin_amdgcn_mfma_f32_16x16x32_bf16(a1, bfr[1][1], acc[rt][1], 0, 0, 0);
        acc[rt][0] = __builtin_amdgcn_mfma_f32_16x16x32_bf16(a2, bfr[2][0], acc[rt][0], 0, 0, 0);
        acc[rt][1] = __builtin_amdgcn_mfma_f32_16x16x32_bf16(a2, bfr[2][1], acc[rt][1], 0, 0, 0);
        acc[rt][0] = __builtin_amdgcn_mfma_f32_16x16x32_bf16(a3, bfr[3][0], acc[rt][0], 0, 0, 0);
        acc[rt][1] = __builtin_amdgcn_mfma_f32_16x16x32_bf16(a3, bfr[3][1], acc[rt][1], 0, 0, 0);
    }

    // ---- epilogue ----
    const float b2_0 = b2[w * 32 + l15];
    const float b2_1 = b2[w * 32 + 16 + l15];
    const float be_0 = be[w * 32 + l15];
    const float be_1 = be[w * 32 + 16 + l15];
    #pragma unroll
    for (int rt = 0; rt < 4; ++rt) {
        const int rbase = row0 + rt * 16 + kg * 4;
        float dgv[4];
        if (rbase + 3 < N) {
            *(float4*)dgv = *(const float4*)(degf + rbase);
        } else {
            #pragma unroll
            for (int j = 0; j < 4; ++j)
                dgv[j] = (rbase + j < N) ? degf[rbase + j] : 0.f;
        }
        #pragma unroll
        for (int j = 0; j < 4; ++j) {
            const int row = rbase + j;
            if (row < N) {
                out[(size_t)row * D + w * 32 + l15] =
                    acc[rt][0][j] + b2_0 + dgv[j] * be_0;
                out[(size_t)row * D + w * 32 + 16 + l15] =
                    acc[rt][1][j] + b2_1 + dgv[j] * be_1;
            }
        }
    }
}

extern "C" void kernel_launch(void* const* d_in, const int* in_sizes, int n_in,
                              void* d_out, int out_size, void* d_ws, size_t ws_size,
                              hipStream_t stream) {
    const float* nfeat = (const float*)d_in[0];
    const float* efeat = (const float*)d_in[1];
    const int*   src   = (const int*)d_in[2];
    const int*   dst   = (const int*)d_in[3];
    const float* W1    = (const float*)d_in[4];
    const float* b1    = (const float*)d_in[5];
    const float* gamma = (const float*)d_in[6];
    const float* beta  = (const float*)d_in[7];
    const float* W2    = (const float*)d_in[8];
    const float* b2    = (const float*)d_in[9];
    const float* We    = (const float*)d_in[10];
    const float* be    = (const float*)d_in[11];
    float* out = (float*)d_out;

    const int N = in_sizes[0] / D;
    const int E = in_sizes[2];
    const size_t ND = (size_t)N * D;

    // workspace layout — every segment a multiple of 16 B (h1 aliases xbuf)
    short* nfb    = (short*)d_ws;                // N*D bf16
    short* xbuf   = nfb + ND;                    // N*D bf16
    short* h1     = xbuf;                        // aliased
    short* agg_e  = xbuf + ND;                   // N*D bf16
    short* Wt1    = agg_e + ND;                  // 16384
    short* Wt2    = Wt1 + 16384;
    short* Wte    = Wt2 + 16384;
    float* stats  = (float*)(Wte + 16384);       // 256
    float* degf   = stats + 256;                 // N
    int*   row_ptr= (int*)(degf + N);            // N+16
    int*   cursor = row_ptr + (N + 16);          // N+16
    int*   cnt    = cursor + (N + 16);           // N+16
    int2*  epair  = (int2*)(cnt + (N + 16));     // E

    const int nbConv = ((N * D) / 4 + 255) / 256;
    const int nbW    = 192;
    const int nbZ    = (N / 4 + 255) / 256;
    const int ebl4   = (E / 4 + 255) / 256;
    const int nb     = (N + 63) / 64;

    k_prep<<<nbConv + nbW + nbZ, 256, 0, stream>>>(nfeat, nfb, W1, W2, We,
                                                   Wt1, Wt2, Wte, cnt, stats,
                                                   N, nbConv, nbW);
    k_hist<<<ebl4, 256, 0, stream>>>(dst, cnt, E);
    k_scan<<<1, 1024, 0, stream>>>(cnt, row_ptr, cursor, degf, N);
    k_scatter<<<ebl4, 256, 0, stream>>>(src, dst, cursor, epair, E);
    k_gather<<<(N + 3) / 4, 256, 0, stream>>>(nfeat, nfb, efeat, row_ptr, epair,
                                              xbuf, agg_e, N);
    k_h1<<<nb, 256, 0, stream>>>(xbuf, Wt1, b1, h1, stats, N);
    k_out<<<nb, 256, 0, stream>>>(h1, agg_e, Wt2, Wte, stats, gamma, beta,
                                  b2, be, degf, out, N);
}

// Round 7
// 285.488 us; speedup vs baseline: 1.2040x; 1.0011x over previous
//
#include <hip/hip_runtime.h>

#define D 128

typedef __attribute__((ext_vector_type(8))) short bf16x8;   // 8 bf16 = 4 VGPR
typedef __attribute__((ext_vector_type(4))) float f32x4;    // MFMA C/D
typedef __attribute__((ext_vector_type(4))) float fx4;      // NT-loadable float4
typedef __attribute__((ext_vector_type(4))) short sx4;      // NT-loadable short4

static __device__ __forceinline__ short f2bf(float f) {  // RNE bf16 bits
    union { float f; unsigned u; } v; v.f = f;
    const unsigned r = v.u + 0x7FFFu + ((v.u >> 16) & 1u);
    return (short)(r >> 16);
}
static __device__ __forceinline__ float bf2f(short s) {
    union { unsigned u; float f; } v;
    v.u = ((unsigned)(unsigned short)s) << 16;
    return v.f;
}

// ===== k_prep: nfeat->bf16 convert, W transpose->bf16, zero cnt/stats =====
__global__ __launch_bounds__(256) void k_prep(
    const float* __restrict__ nfeat, short* __restrict__ nfb,
    const float* __restrict__ W1, const float* __restrict__ W2,
    const float* __restrict__ We, short* __restrict__ Wt1,
    short* __restrict__ Wt2, short* __restrict__ Wte,
    int* __restrict__ cnt, float* __restrict__ stats,
    int N, int nbConv, int nbW)
{
    const int b = blockIdx.x, t = threadIdx.x;
    if (b < nbConv) {
        const int i = b * 256 + t;
        if (i < (N * D) / 4) {
            const float4 v = ((const float4*)nfeat)[i];
            short4 s;
            s.x = f2bf(v.x); s.y = f2bf(v.y); s.z = f2bf(v.z); s.w = f2bf(v.w);
            ((short4*)nfb)[i] = s;
        }
    } else if (b < nbConv + nbW) {
        const int i = (b - nbConv) * 256 + t;   // 0 .. 49151
        const int m = i >> 14;
        const int idx = i & 16383;
        const int k = idx >> 7, n = idx & 127;
        const float* W = (m == 0) ? W1 : (m == 1) ? W2 : We;
        short* Wt = (m == 0) ? Wt1 : (m == 1) ? Wt2 : Wte;
        Wt[n * 128 + k] = f2bf(W[k * 128 + n]);
    } else {
        const int i = (b - nbConv - nbW) * 256 + t;
        if (i * 4 < N) ((int4*)cnt)[i] = make_int4(0, 0, 0, 0);
        if (b == nbConv + nbW && t < 256) stats[t] = 0.f;
    }
}

// ================= CSR build =================
__global__ void k_hist(const int* __restrict__ dst, int* __restrict__ cnt, int E) {
    const int base = (blockIdx.x * 256 + threadIdx.x) * 4;
    if (base + 3 < E) {
        const int4 d4 = *(const int4*)(dst + base);
        atomicAdd(&cnt[d4.x], 1);
        atomicAdd(&cnt[d4.y], 1);
        atomicAdd(&cnt[d4.z], 1);
        atomicAdd(&cnt[d4.w], 1);
    } else {
        for (int e = base; e < E; ++e) atomicAdd(&cnt[dst[e]], 1);
    }
}

// ===== single-block multi-tile exclusive scan =====
__global__ __launch_bounds__(1024) void k_scan(
    const int* __restrict__ cnt, int* __restrict__ row_ptr,
    int* __restrict__ cursor, float* __restrict__ degf, int N)
{
    __shared__ int ws[17];
    const int t = threadIdx.x, lane = t & 63, wid = t >> 6;
    int carry = 0;
    const int ntiles = (N + 4095) / 4096;
    for (int tile = 0; tile < ntiles; ++tile) {
        const int base = tile * 4096 + t * 4;
        int4 v = make_int4(0, 0, 0, 0);
        if (base + 3 < N) v = *(const int4*)(cnt + base);
        else {
            if (base     < N) v.x = cnt[base];
            if (base + 1 < N) v.y = cnt[base + 1];
            if (base + 2 < N) v.z = cnt[base + 2];
            if (base + 3 < N) v.w = cnt[base + 3];
        }
        const int s = v.x + v.y + v.z + v.w;
        int incl = s;
        #pragma unroll
        for (int off = 1; off < 64; off <<= 1) {
            const int u = __shfl_up(incl, off);
            if (lane >= off) incl += u;
        }
        if (lane == 63) ws[wid] = incl;
        __syncthreads();
        if (t < 16) {
            const int wv = ws[t];
            int wincl = wv;
            #pragma unroll
            for (int off = 1; off < 16; off <<= 1) {
                const int u = __shfl_up(wincl, off);
                if (t >= off) wincl += u;
            }
            ws[t] = wincl - wv;
            if (t == 15) ws[16] = wincl;
        }
        __syncthreads();
        const int ex = carry + ws[wid] + (incl - s);
        if (base + 3 < N) {
            const int4 rp = make_int4(ex, ex + v.x, ex + v.x + v.y,
                                      ex + v.x + v.y + v.z);
            *(int4*)(row_ptr + base) = rp;
            *(int4*)(cursor + base)  = rp;
            *(float4*)(degf + base)  =
                make_float4((float)v.x, (float)v.y, (float)v.z, (float)v.w);
        } else {
            int run = ex;
            if (base < N)     { row_ptr[base]   = run; cursor[base]   = run; degf[base]   = (float)v.x; run += v.x; }
            if (base + 1 < N) { row_ptr[base+1] = run; cursor[base+1] = run; degf[base+1] = (float)v.y; run += v.y; }
            if (base + 2 < N) { row_ptr[base+2] = run; cursor[base+2] = run; degf[base+2] = (float)v.z; run += v.z; }
            if (base + 3 < N) { row_ptr[base+3] = run; cursor[base+3] = run; degf[base+3] = (float)v.w; }
        }
        carry += ws[16];
        __syncthreads();
    }
    if (t == 0) row_ptr[N] = carry;
}

__global__ void k_scatter(const int* __restrict__ src, const int* __restrict__ dst,
                          int* __restrict__ cursor,
                          int2* __restrict__ epair, int E) {
    const int base = (blockIdx.x * 256 + threadIdx.x) * 4;
    if (base + 3 < E) {
        const int4 d4 = *(const int4*)(dst + base);
        const int4 s4 = *(const int4*)(src + base);
        int p;
        p = atomicAdd(&cursor[d4.x], 1); epair[p] = make_int2(base + 0, s4.x);
        p = atomicAdd(&cursor[d4.y], 1); epair[p] = make_int2(base + 1, s4.y);
        p = atomicAdd(&cursor[d4.z], 1); epair[p] = make_int2(base + 2, s4.z);
        p = atomicAdd(&cursor[d4.w], 1); epair[p] = make_int2(base + 3, s4.w);
    } else {
        for (int e = base; e < E; ++e) {
            const int p = atomicAdd(&cursor[dst[e]], 1);
            epair[p] = make_int2(e, src[e]);
        }
    }
}

// ===== gather: HALF-WAVE per node (8 nodes/block), 4 edges in flight =====
// xbuf = bf16(nfb[node] + sum nfb[src]); agg_e = bf16(sum efeat[e])
// efeat read via NT loads (read-once stream: keep L2/L3 for nfb/epair);
// xbuf/agg_e written via NT stores (consumed later by other kernels).
__global__ __launch_bounds__(256) void k_gather(
    const short* __restrict__ nfb, const float* __restrict__ efeat,
    const int* __restrict__ row_ptr, const int2* __restrict__ epair,
    short* __restrict__ xbuf, short* __restrict__ agg_e, int N)
{
    const int t = threadIdx.x;
    const int c = t & 31;                  // float4/short4 chunk of the row
    const int node = blockIdx.x * 8 + (t >> 5);
    if (node >= N) return;

    const int start = row_ptr[node];
    const int end   = row_ptr[node + 1];

    fx4 an = {0.f, 0.f, 0.f, 0.f};
    fx4 ae = {0.f, 0.f, 0.f, 0.f};
    int e = start;
    for (; e + 3 < end; e += 4) {          // 4 edges in flight per half-wave
        const int2 p0 = epair[e];
        const int2 p1 = epair[e + 1];
        const int2 p2 = epair[e + 2];
        const int2 p3 = epair[e + 3];
        const fx4 ev0 = __builtin_nontemporal_load((const fx4*)(efeat + (size_t)p0.x * D) + c);
        const fx4 ev1 = __builtin_nontemporal_load((const fx4*)(efeat + (size_t)p1.x * D) + c);
        const fx4 ev2 = __builtin_nontemporal_load((const fx4*)(efeat + (size_t)p2.x * D) + c);
        const fx4 ev3 = __builtin_nontemporal_load((const fx4*)(efeat + (size_t)p3.x * D) + c);
        const sx4 nv0 = *((const sx4*)(nfb + (size_t)p0.y * D) + c);
        const sx4 nv1 = *((const sx4*)(nfb + (size_t)p1.y * D) + c);
        const sx4 nv2 = *((const sx4*)(nfb + (size_t)p2.y * D) + c);
        const sx4 nv3 = *((const sx4*)(nfb + (size_t)p3.y * D) + c);
        #pragma unroll
        for (int j = 0; j < 4; ++j) {
            ae[j] += (ev0[j] + ev1[j]) + (ev2[j] + ev3[j]);
            an[j] += (bf2f(nv0[j]) + bf2f(nv1[j])) + (bf2f(nv2[j]) + bf2f(nv3[j]));
        }
    }
    for (; e < end; ++e) {
        const int2 p0 = epair[e];
        const fx4 ev0 = __builtin_nontemporal_load((const fx4*)(efeat + (size_t)p0.x * D) + c);
        const sx4 nv0 = *((const sx4*)(nfb + (size_t)p0.y * D) + c);
        #pragma unroll
        for (int j = 0; j < 4; ++j) {
            ae[j] += ev0[j];
            an[j] += bf2f(nv0[j]);
        }
    }

    const sx4 self = *((const sx4*)(nfb + (size_t)node * D) + c);
    sx4 xv, ev2;
    #pragma unroll
    for (int j = 0; j < 4; ++j) {
        xv[j]  = f2bf(bf2f(self[j]) + an[j]);
        ev2[j] = f2bf(ae[j]);
    }
    __builtin_nontemporal_store(xv,  (sx4*)(xbuf  + (size_t)node * D) + c);
    __builtin_nontemporal_store(ev2, (sx4*)(agg_e + (size_t)node * D) + c);
}

// ======= k_h1: h1 = xbuf @ W1 + b1 (bf16 MFMA), + BN stats atomics =======
// 64 rows/block, 4 waves; wave w owns cols [w*32, w*32+32)
// NOTE: xbuf and h1 alias (reads complete before epilogue writes) — no restrict
__global__ __launch_bounds__(256) void k_h1(const short* xbuf,
                                            const short* __restrict__ Wt1,
                                            const float* __restrict__ b1,
                                            short* h1,
                                            float* __restrict__ stats, int N) {
    const int t = threadIdx.x;
    const int lane = t & 63;
    const int w = t >> 6;
    const int l15 = lane & 15;
    const int kg = lane >> 4;
    const int row0 = blockIdx.x * 64;

    bf16x8 bfr[4][2];
    #pragma unroll
    for (int kt = 0; kt < 4; ++kt)
        #pragma unroll
        for (int cf = 0; cf < 2; ++cf)
            bfr[kt][cf] = *(const bf16x8*)(Wt1 + (w * 32 + cf * 16 + l15) * D +
                                           kt * 32 + kg * 8);

    f32x4 acc[4][2];
    #pragma unroll
    for (int rt = 0; rt < 4; ++rt) { acc[rt][0] = (f32x4)0.f; acc[rt][1] = (f32x4)0.f; }

    #pragma unroll
    for (int rt = 0; rt < 4; ++rt) {
        const int row = row0 + rt * 16 + l15;
        bf16x8 a0 = (bf16x8)(short)0, a1 = a0, a2 = a0, a3 = a0;
        if (row < N) {
            const short* xp = xbuf + (size_t)row * D + kg * 8;
            a0 = *(const bf16x8*)(xp);
            a1 = *(const bf16x8*)(xp + 32);
            a2 = *(const bf16x8*)(xp + 64);
            a3 = *(const bf16x8*)(xp + 96);
        }
        acc[rt][0] = __builtin_amdgcn_mfma_f32_16x16x32_bf16(a0, bfr[0][0], acc[rt][0], 0, 0, 0);
        acc[rt][1] = __builtin_amdgcn_mfma_f32_16x16x32_bf16(a0, bfr[0][1], acc[rt][1], 0, 0, 0);
        acc[rt][0] = __builtin_amdgcn_mfma_f32_16x16x32_bf16(a1, bfr[1][0], acc[rt][0], 0, 0, 0);
        acc[rt][1] = __builtin_amdgcn_mfma_f32_16x16x32_bf16(a1, bfr[1][1], acc[rt][1], 0, 0, 0);
        acc[rt][0] = __builtin_amdgcn_mfma_f32_16x16x32_bf16(a2, bfr[2][0], acc[rt][0], 0, 0, 0);
        acc[rt][1] = __builtin_amdgcn_mfma_f32_16x16x32_bf16(a2, bfr[2][1], acc[rt][1], 0, 0, 0);
        acc[rt][0] = __builtin_amdgcn_mfma_f32_16x16x32_bf16(a3, bfr[3][0], acc[rt][0], 0, 0, 0);
        acc[rt][1] = __builtin_amdgcn_mfma_f32_16x16x32_bf16(a3, bfr[3][1], acc[rt][1], 0, 0, 0);
    }

    const float bias0 = b1[w * 32 + l15];
    const float bias1 = b1[w * 32 + 16 + l15];
    float cs0 = 0.f, cq0 = 0.f, cs1 = 0.f, cq1 = 0.f;
    #pragma unroll
    for (int rt = 0; rt < 4; ++rt) {
        #pragma unroll
        for (int j = 0; j < 4; ++j) {
            const int row = row0 + rt * 16 + kg * 4 + j;
            if (row < N) {
                const float h0 = acc[rt][0][j] + bias0;
                const float hv = acc[rt][1][j] + bias1;
                h1[(size_t)row * D + w * 32 + l15]      = f2bf(h0);
                h1[(size_t)row * D + w * 32 + 16 + l15] = f2bf(hv);
                cs0 += h0; cq0 += h0 * h0;
                cs1 += hv; cq1 += hv * hv;
            }
        }
    }
    #pragma unroll
    for (int m = 16; m < 64; m <<= 1) {
        cs0 += __shfl_xor(cs0, m); cq0 += __shfl_xor(cq0, m);
        cs1 += __shfl_xor(cs1, m); cq1 += __shfl_xor(cq1, m);
    }
    if (lane < 16) {
        atomicAdd(stats + w * 32 + lane,            cs0);
        atomicAdd(stats + w * 32 + 16 + lane,       cs1);
        atomicAdd(stats + 128 + w * 32 + lane,      cq0);
        atomicAdd(stats + 128 + w * 32 + 16 + lane, cq1);
    }
}

// ==== k_out: out = relu(bn(h1))@W2 + agg_e@We + b2 + deg*be (bf16 MFMA) ====
__global__ __launch_bounds__(256) void k_out(const short* __restrict__ h1,
                                             const short* __restrict__ agg_e,
                                             const short* __restrict__ Wt2,
                                             const short* __restrict__ Wte,
                                             const float* __restrict__ stats,
                                             const float* __restrict__ gamma,
                                             const float* __restrict__ beta,
                                             const float* __restrict__ b2,
                                             const float* __restrict__ be,
                                             const float* __restrict__ degf,
                                             float* __restrict__ out, int N) {
    __shared__ float scs[128], shs[128];
    const int t = threadIdx.x;
    if (t < 128) {
        const float invN = 1.0f / (float)N;
        const float mu = stats[t] * invN;
        const float var = stats[128 + t] * invN - mu * mu;
        const float sc = gamma[t] * rsqrtf(var + 1e-5f);
        scs[t] = sc;
        shs[t] = beta[t] - mu * sc;
    }
    __syncthreads();

    const int lane = t & 63;
    const int w = t >> 6;
    const int l15 = lane & 15;
    const int kg = lane >> 4;
    const int row0 = blockIdx.x * 64;

    f32x4 acc[4][2];
    #pragma unroll
    for (int rt = 0; rt < 4; ++rt) { acc[rt][0] = (f32x4)0.f; acc[rt][1] = (f32x4)0.f; }

    bf16x8 bfr[4][2];

    // ---- phase A: relu(bn(h1)) @ W2 ----
    #pragma unroll
    for (int kt = 0; kt < 4; ++kt)
        #pragma unroll
        for (int cf = 0; cf < 2; ++cf)
            bfr[kt][cf] = *(const bf16x8*)(Wt2 + (w * 32 + cf * 16 + l15) * D +
                                           kt * 32 + kg * 8);

    #pragma unroll
    for (int rt = 0; rt < 4; ++rt) {
        const int row = row0 + rt * 16 + l15;
        #pragma unroll
        for (int kt = 0; kt < 4; ++kt) {
            bf16x8 raw = (bf16x8)(short)0;
            if (row < N)
                raw = *(const bf16x8*)(h1 + (size_t)row * D + kt * 32 + kg * 8);
            const int k0 = kt * 32 + kg * 8;
            const float4 sa = *(const float4*)(scs + k0);
            const float4 sb = *(const float4*)(scs + k0 + 4);
            const float4 ha = *(const float4*)(shs + k0);
            const float4 hb = *(const float4*)(shs + k0 + 4);
            bf16x8 afr;
            afr[0] = f2bf(fmaxf(bf2f(raw[0]) * sa.x + ha.x, 0.f));
            afr[1] = f2bf(fmaxf(bf2f(raw[1]) * sa.y + ha.y, 0.f));
            afr[2] = f2bf(fmaxf(bf2f(raw[2]) * sa.z + ha.z, 0.f));
            afr[3] = f2bf(fmaxf(bf2f(raw[3]) * sa.w + ha.w, 0.f));
            afr[4] = f2bf(fmaxf(bf2f(raw[4]) * sb.x + hb.x, 0.f));
            afr[5] = f2bf(fmaxf(bf2f(raw[5]) * sb.y + hb.y, 0.f));
            afr[6] = f2bf(fmaxf(bf2f(raw[6]) * sb.z + hb.z, 0.f));
            afr[7] = f2bf(fmaxf(bf2f(raw[7]) * sb.w + hb.w, 0.f));
            acc[rt][0] = __builtin_amdgcn_mfma_f32_16x16x32_bf16(afr, bfr[kt][0], acc[rt][0], 0, 0, 0);
            acc[rt][1] = __builtin_amdgcn_mfma_f32_16x16x32_bf16(afr, bfr[kt][1], acc[rt][1], 0, 0, 0);
        }
    }

    // ---- phase B: agg_e @ We ----
    #pragma unroll
    for (int kt = 0; kt < 4; ++kt)
        #pragma unroll
        for (int cf = 0; cf < 2; ++cf)
            bfr[kt][cf] = *(const bf16x8*)(Wte + (w * 32 + cf * 16 + l15) * D +
                                           kt * 32 + kg * 8);

    #pragma unroll
    for (int rt = 0; rt < 4; ++rt) {
        const int row = row0 + rt * 16 + l15;
        bf16x8 a0 = (bf16x8)(short)0, a1 = a0, a2 = a0, a3 = a0;
        if (row < N) {
            const short* ap = agg_e + (size_t)row * D + kg * 8;
            a0 = *(const bf16x8*)(ap);
            a1 = *(const bf16x8*)(ap + 32);
            a2 = *(const bf16x8*)(ap + 64);
            a3 = *(const bf16x8*)(ap + 96);
        }
        acc[rt][0] = __builtin_amdgcn_mfma_f32_16x16x32_bf16(a0, bfr[0][0], acc[rt][0], 0, 0, 0);
        acc[rt][1] = __builtin_amdgcn_mfma_f32_16x16x32_bf16(a0, bfr[0][1], acc[rt][1], 0, 0, 0);
        acc[rt][0] = __builtin_amdgcn_mfma_f32_16x16x32_bf16(a1, bfr[1][0], acc[rt][0], 0, 0, 0);
        acc[rt][1] = __builtin_amdgcn_mfma_f32_16x16x32_bf16(a1, bfr[1][1], acc[rt][1], 0, 0, 0);
        acc[rt][0] = __builtin_amdgcn_mfma_f32_16x16x32_bf16(a2, bfr[2][0], acc[rt][0], 0, 0, 0);
        acc[rt][1] = __builtin_amdgcn_mfma_f32_16x16x32_bf16(a2, bfr[2][1], acc[rt][1], 0, 0, 0);
        acc[rt][0] = __builtin_amdgcn_mfma_f32_16x16x32_bf16(a3, bfr[3][0], acc[rt][0], 0, 0, 0);
        acc[rt][1] = __builtin_amdgcn_mfma_f32_16x16x32_bf16(a3, bfr[3][1], acc[rt][1], 0, 0, 0);
    }

    // ---- epilogue ----
    const float b2_0 = b2[w * 32 + l15];
    const float b2_1 = b2[w * 32 + 16 + l15];
    const float be_0 = be[w * 32 + l15];
    const float be_1 = be[w * 32 + 16 + l15];
    #pragma unroll
    for (int rt = 0; rt < 4; ++rt) {
        const int rbase = row0 + rt * 16 + kg * 4;
        float dgv[4];
        if (rbase + 3 < N) {
            *(float4*)dgv = *(const float4*)(degf + rbase);
        } else {
            #pragma unroll
            for (int j = 0; j < 4; ++j)
                dgv[j] = (rbase + j < N) ? degf[rbase + j] : 0.f;
        }
        #pragma unroll
        for (int j = 0; j < 4; ++j) {
            const int row = rbase + j;
            if (row < N) {
                out[(size_t)row * D + w * 32 + l15] =
                    acc[rt][0][j] + b2_0 + dgv[j] * be_0;
                out[(size_t)row * D + w * 32 + 16 + l15] =
                    acc[rt][1][j] + b2_1 + dgv[j] * be_1;
            }
        }
    }
}

extern "C" void kernel_launch(void* const* d_in, const int* in_sizes, int n_in,
                              void* d_out, int out_size, void* d_ws, size_t ws_size,
                              hipStream_t stream) {
    const float* nfeat = (const float*)d_in[0];
    const float* efeat = (const float*)d_in[1];
    const int*   src   = (const int*)d_in[2];
    const int*   dst   = (const int*)d_in[3];
    const float* W1    = (const float*)d_in[4];
    const float* b1    = (const float*)d_in[5];
    const float* gamma = (const float*)d_in[6];
    const float* beta  = (const float*)d_in[7];
    const float* W2    = (const float*)d_in[8];
    const float* b2    = (const float*)d_in[9];
    const float* We    = (const float*)d_in[10];
    const float* be    = (const float*)d_in[11];
    float* out = (float*)d_out;

    const int N = in_sizes[0] / D;
    const int E = in_sizes[2];
    const size_t ND = (size_t)N * D;

    // workspace layout — every segment a multiple of 16 B (h1 aliases xbuf)
    short* nfb    = (short*)d_ws;                // N*D bf16
    short* xbuf   = nfb + ND;                    // N*D bf16
    short* h1     = xbuf;                        // aliased
    short* agg_e  = xbuf + ND;                   // N*D bf16
    short* Wt1    = agg_e + ND;                  // 16384
    short* Wt2    = Wt1 + 16384;
    short* Wte    = Wt2 + 16384;
    float* stats  = (float*)(Wte + 16384);       // 256
    float* degf   = stats + 256;                 // N
    int*   row_ptr= (int*)(degf + N);            // N+16
    int*   cursor = row_ptr + (N + 16);          // N+16
    int*   cnt    = cursor + (N + 16);           // N+16
    int2*  epair  = (int2*)(cnt + (N + 16));     // E

    const int nbConv = ((N * D) / 4 + 255) / 256;
    const int nbW    = 192;
    const int nbZ    = (N / 4 + 255) / 256;
    const int ebl4   = (E / 4 + 255) / 256;
    const int nb     = (N + 63) / 64;

    k_prep<<<nbConv + nbW + nbZ, 256, 0, stream>>>(nfeat, nfb, W1, W2, We,
                                                   Wt1, Wt2, Wte, cnt, stats,
                                                   N, nbConv, nbW);
    k_hist<<<ebl4, 256, 0, stream>>>(dst, cnt, E);
    k_scan<<<1, 1024, 0, stream>>>(cnt, row_ptr, cursor, degf, N);
    k_scatter<<<ebl4, 256, 0, stream>>>(src, dst, cursor, epair, E);
    k_gather<<<(N + 7) / 8, 256, 0, stream>>>(nfb, efeat, row_ptr, epair,
                                              xbuf, agg_e, N);
    k_h1<<<nb, 256, 0, stream>>>(xbuf, Wt1, b1, h1, stats, N);
    k_out<<<nb, 256, 0, stream>>>(h1, agg_e, Wt2, Wte, stats, gamma, beta,
                                  b2, be, degf, out, N);
}